// Round 4
// baseline (524.303 us; speedup 1.0000x reference)
//
#include <hip/hip_runtime.h>

#define N_NODES 100000
#define D 64
#define NB 391              // ceil(100000 / 256) bins of 256 rows
#define ROWS_PER_BIN 256
#define PE 8192             // edges per partition block

typedef unsigned int u32;

__device__ __forceinline__ float bf16_to_f32(unsigned short u) {
    union { u32 i; float f; } c; c.i = ((u32)u) << 16; return c.f;
}
__device__ __forceinline__ unsigned short f32_to_bf16(float f) {
    union { float f; u32 i; } c; c.f = f;
    const u32 u = c.i;
    return (unsigned short)((u + 0x7FFFu + ((u >> 16) & 1u)) >> 16);
}

// ---------------- y = bf16(x @ W^T); block 0 zeroes binCounts ----------------
__global__ __launch_bounds__(256) void xw_kernel(const float* __restrict__ x,
                                                 const float* __restrict__ W,
                                                 unsigned short* __restrict__ y,
                                                 int* __restrict__ binCounts) {
    __shared__ float Ws[D][D + 1];
    __shared__ float xs[32][D];

    const int tid = threadIdx.x;
    if (blockIdx.x == 0) {
        for (int i = tid; i < NB; i += 256) binCounts[i] = 0;
    }
    for (int i = tid; i < D * D; i += 256) Ws[i >> 6][i & 63] = W[i];

    const int nodeBase = blockIdx.x * 32;
    for (int i = tid; i < 32 * D; i += 256) {
        const int n = nodeBase + (i >> 6);
        xs[i >> 6][i & 63] = (n < N_NODES) ? x[n * D + (i & 63)] : 0.f;
    }
    __syncthreads();

    const int wave = tid >> 6, j = tid & 63;
    for (int s = 0; s < 8; ++s) {
        const int local = wave * 8 + s;
        const int n = nodeBase + local;
        if (n >= N_NODES) break;
        float acc = 0.f;
#pragma unroll
        for (int k = 0; k < D; ++k) acc += xs[local][k] * Ws[j][k];
        y[n * D + j] = f32_to_bf16(acc);
    }
}

// ---------------- per-block LDS histogram of row>>8 ----------------
__global__ __launch_bounds__(256) void binhist_kernel(const int* __restrict__ erow,
                                                      int* __restrict__ binCounts, int ne) {
    __shared__ int h[NB];
    for (int i = threadIdx.x; i < NB; i += 256) h[i] = 0;
    __syncthreads();
    const int stride = gridDim.x * 256;
    for (int e = blockIdx.x * 256 + threadIdx.x; e < ne; e += stride)
        atomicAdd(&h[erow[e] >> 8], 1);
    __syncthreads();
    for (int i = threadIdx.x; i < NB; i += 256)
        if (h[i]) atomicAdd(&binCounts[i], h[i]);
}

// ---------------- single-block scan of 391 bin counts ----------------
__global__ __launch_bounds__(512) void binscan_kernel(const int* __restrict__ binCounts,
                                                      int* __restrict__ binOff,
                                                      int* __restrict__ binCursor) {
    __shared__ int s[512];
    const int tid = threadIdx.x;
    const int v = (tid < NB) ? binCounts[tid] : 0;
    s[tid] = v;
    __syncthreads();
    for (int d = 1; d < 512; d <<= 1) {
        const int t = (tid >= d) ? s[tid - d] : 0;
        __syncthreads();
        s[tid] += t;
        __syncthreads();
    }
    if (tid < NB) {
        const int excl = s[tid] - v;
        binOff[tid] = excl;
        binCursor[tid] = excl;
        if (tid == NB - 1) binOff[NB] = s[tid];
    }
}

// ---------------- partition: bin-grouped packed edges, block-contiguous runs ----------------
__global__ __launch_bounds__(256) void partition_kernel(const int* __restrict__ erow,
                                                        const int* __restrict__ ecol,
                                                        const float* __restrict__ eval_,
                                                        int* __restrict__ binCursor,
                                                        uint2* __restrict__ pedge, int ne) {
    __shared__ int h[NB];
    __shared__ int lcur[NB];
    for (int i = threadIdx.x; i < NB; i += 256) h[i] = 0;
    __syncthreads();
    const int base = blockIdx.x * PE;
    const int end  = min(base + PE, ne);
    for (int e = base + threadIdx.x; e < end; e += 256)
        atomicAdd(&h[erow[e] >> 8], 1);
    __syncthreads();
    for (int i = threadIdx.x; i < NB; i += 256) {
        const int c = h[i];
        lcur[i] = c ? atomicAdd(&binCursor[i], c) : 0;
    }
    __syncthreads();
    for (int e = base + threadIdx.x; e < end; e += 256) {
        const int r = erow[e];
        const int bin = r >> 8;
        const int pos = atomicAdd(&lcur[bin], 1);
        int q = (int)(eval_[e] * 32768.0f + 0.5f);
        q = (q > 32767) ? 32767 : q;
        uint2 pk;
        pk.x = ((u32)ecol[e] << 15) | (u32)q;
        pk.y = (u32)(r & 255);
        pedge[pos] = pk;
    }
}

// ---------------- aggregate: one block per bin, LDS f32 accumulators ----------------
__global__ __launch_bounds__(256) void aggregate_kernel(const int* __restrict__ binOff,
                                                        const uint2* __restrict__ pedge,
                                                        const unsigned short* __restrict__ y,
                                                        const float* __restrict__ b,
                                                        float4* __restrict__ out4) {
    __shared__ float acc[ROWS_PER_BIN * D];    // 64 KB
    __shared__ float bs[D];
    const int tid = threadIdx.x;
    for (int i = tid; i < ROWS_PER_BIN * D; i += 256) acc[i] = 0.f;
    if (tid < D) bs[tid] = b[tid];
    __syncthreads();

    const int bin  = blockIdx.x;
    const int s    = binOff[bin];
    const int e    = binOff[bin + 1];
    const int lane = tid & 63;
    const int w    = tid >> 6;

    // wave w handles 8-edge batches starting at s + w*8, stride 32
    for (int bb = s + w * 8; bb < e; bb += 32) {
        u32 lo[8]; int rr[8]; float vv[8]; unsigned short g[8];
#pragma unroll
        for (int j = 0; j < 8; ++j) {
            const int idx = bb + j;
            const int ii  = min(idx, e - 1);       // clamp: always a valid in-bin entry
            const uint2 ed = pedge[ii];
            lo[j] = ed.x;
            rr[j] = (int)ed.y;
            vv[j] = (idx < e) ? ((float)(ed.x & 32767u) * (1.0f / 32768.0f)) : 0.f;
        }
#pragma unroll
        for (int j = 0; j < 8; ++j) {
            g[j] = y[(int)(lo[j] >> 15) * D + lane];   // coalesced 128B row gather
        }
#pragma unroll
        for (int j = 0; j < 8; ++j) {
            atomicAdd(&acc[rr[j] * D + lane], vv[j] * bf16_to_f32(g[j]));  // ds_add_f32
        }
    }
    __syncthreads();

    // dense writeout + bias
    const int rowBase = bin * ROWS_PER_BIN;
    for (int i = tid; i < ROWS_PER_BIN * 16; i += 256) {
        const int rl = i >> 4, q = i & 15;
        const int row = rowBase + rl;
        if (row < N_NODES) {
            const float4 a  = ((const float4*)acc)[i];
            const float4 bv = ((const float4*)bs)[q];
            out4[row * 16 + q] = make_float4(a.x + bv.x, a.y + bv.y, a.z + bv.z, a.w + bv.w);
        }
    }
}

// ---------------- fallback (small ws): atomic scatter ----------------
__global__ __launch_bounds__(256) void init_out_kernel(const float* __restrict__ b,
                                                       float* __restrict__ out) {
    const int i = blockIdx.x * blockDim.x + threadIdx.x;
    const int total4 = N_NODES * D / 4;
    if (i < total4) {
        const float4* b4 = reinterpret_cast<const float4*>(b);
        reinterpret_cast<float4*>(out)[i] = b4[i & 15];
    }
}

__global__ __launch_bounds__(256) void scatter_kernel(const int* __restrict__ erow,
                                                      const int* __restrict__ ecol,
                                                      const float* __restrict__ eval_,
                                                      const unsigned short* __restrict__ y,
                                                      float* __restrict__ out, int ne) {
    const int e    = blockIdx.x * 4 + (threadIdx.x >> 6);
    const int lane = threadIdx.x & 63;
    if (e >= ne) return;
    atomicAdd(&out[erow[e] * D + lane], eval_[e] * bf16_to_f32(y[ecol[e] * D + lane]));
}

extern "C" void kernel_launch(void* const* d_in, const int* in_sizes, int n_in,
                              void* d_out, int out_size, void* d_ws, size_t ws_size,
                              hipStream_t stream) {
    const float* x     = (const float*)d_in[0];
    const int*   erow  = (const int*)  d_in[1];
    const int*   ecol  = (const int*)  d_in[2];
    const float* eval_ = (const float*)d_in[3];
    const float* W     = (const float*)d_in[4];
    const float* b     = (const float*)d_in[5];
    float*       out   = (float*)d_out;
    const int ne = in_sizes[1];

    char* ws = (char*)d_ws;
    // workspace layout
    const size_t Y_OFF     = 0;              // 100000*64*2 = 12,800,000 B
    const size_t PEDGE_OFF = 12800000;       // 1M * 8B = 8,000,000 B (8-aligned)
    const size_t BCNT_OFF  = 20800000;       // 391*4
    const size_t BOFF_OFF  = 20801600;       // 392*4
    const size_t BCUR_OFF  = 20803200;       // 391*4
    const size_t TOTAL     = 20804800;

    unsigned short* y = (unsigned short*)(ws + Y_OFF);

    if (ws_size >= TOTAL) {
        uint2* pedge     = (uint2*)(ws + PEDGE_OFF);
        int*   binCounts = (int*)  (ws + BCNT_OFF);
        int*   binOff    = (int*)  (ws + BOFF_OFF);
        int*   binCursor = (int*)  (ws + BCUR_OFF);

        // 1) y = bf16(x @ W^T); zeroes binCounts
        xw_kernel<<<3125, 256, 0, stream>>>(x, W, y, binCounts);

        // 2) coarse CSR (391 bins of 256 rows)
        binhist_kernel<<<256, 256, 0, stream>>>(erow, binCounts, ne);
        binscan_kernel<<<1, 512, 0, stream>>>(binCounts, binOff, binCursor);
        partition_kernel<<<(ne + PE - 1) / PE, 256, 0, stream>>>(erow, ecol, eval_, binCursor, pedge, ne);

        // 3) per-bin LDS-accumulated aggregation + bias
        aggregate_kernel<<<NB, 256, 0, stream>>>(binOff, pedge, y, b, (float4*)out);
    } else {
        xw_kernel<<<3125, 256, 0, stream>>>(x, W, y, (int*)(ws + (ws_size > 13000000 ? 12800000 : 0)));
        init_out_kernel<<<(N_NODES * D / 4 + 255) / 256, 256, 0, stream>>>(b, out);
        scatter_kernel<<<(ne + 3) / 4, 256, 0, stream>>>(erow, ecol, eval_, y, out, ne);
    }
}